// Round 1
// baseline (1615.314 us; speedup 1.0000x reference)
//
#include <hip/hip_runtime.h>
#include <math.h>

#define SLEN 2048
#define ND 256
#define NHEADS 24
#define HC 64
#define VROW 6144
#define TWO_PI 6.283185307179586f

// ---------------- zero d_out ----------------
__global__ __launch_bounds__(256) void zero_out_kernel(float4* __restrict__ out) {
    out[(size_t)blockIdx.x * 256 + threadIdx.x] = make_float4(0.f, 0.f, 0.f, 0.f);
}

// ---------------- K1: k/q projections ----------------
// grid 256: sb = bid&127 (16 s-rows), oh = bid>>7 (512 of 1024 outputs)
__global__ __launch_bounds__(256) void kq_kernel(
    const float* __restrict__ nodes, const float* __restrict__ pos,
    const float* __restrict__ aux,
    const float* __restrict__ Wn, const float* __restrict__ bn,
    const float* __restrict__ Wp, const float* __restrict__ bp,
    const float* __restrict__ Wa,
    float* __restrict__ kbuf, float* __restrict__ qbuf)
{
    __shared__ float n_lds[16][256];
    __shared__ float pf_lds[16][6];
    __shared__ float a_lds[16][16];
    const int tid = threadIdx.x;
    const int sb = blockIdx.x & 127;
    const int oh = blockIdx.x >> 7;
    const int s0 = sb * 16;

    #pragma unroll
    for (int p = 0; p < 4; ++p) {
        int u = tid * 4 + p;          // 0..1023
        int r = u >> 6, c4 = u & 63;
        float4 v = *(const float4*)(nodes + (size_t)(s0 + r) * ND + c4 * 4);
        *(float4*)(&n_lds[r][c4 * 4]) = v;
    }
    if (tid < 48) {
        int r = tid / 3, c = tid % 3;
        float pv = pos[(s0 + r) * 3 + c] * TWO_PI;
        pf_lds[r][c] = cosf(pv);
        pf_lds[r][c + 3] = sinf(pv);
    }
    if (tid < 256 && tid >= 0) {
        if (tid < 16 * 16) {
            int r = tid >> 4, c = tid & 15;
            a_lds[r][c] = aux[(s0 + r) * 16 + c];
        }
    }
    __syncthreads();

    for (int rr = 0; rr < 2; ++rr) {
        const int o = oh * 512 + rr * 256 + tid;  // 0..1023
        float accn[16];
        const float bnv = bn[o];
        #pragma unroll
        for (int ss = 0; ss < 16; ++ss) accn[ss] = bnv;
        const float4* wrow = (const float4*)(Wn + (size_t)o * ND);
        for (int d4 = 0; d4 < 64; ++d4) {
            float4 w = wrow[d4];
            #pragma unroll
            for (int ss = 0; ss < 16; ++ss) {
                const float* n = &n_lds[ss][d4 * 4];
                accn[ss] += n[0] * w.x + n[1] * w.y + n[2] * w.z + n[3] * w.w;
            }
        }
        float accp[16];
        const float bpv = bp[o];
        float wpv[6];
        #pragma unroll
        for (int d = 0; d < 6; ++d) wpv[d] = Wp[(size_t)o * 6 + d];
        #pragma unroll
        for (int ss = 0; ss < 16; ++ss) {
            float a = bpv;
            #pragma unroll
            for (int d = 0; d < 6; ++d) a += pf_lds[ss][d] * wpv[d];
            accp[ss] = a;
        }
        float acca[16];
        float wav[16];
        #pragma unroll
        for (int d = 0; d < 16; ++d) wav[d] = Wa[(size_t)o * 16 + d];
        #pragma unroll
        for (int ss = 0; ss < 16; ++ss) {
            float a = 0.f;
            #pragma unroll
            for (int d = 0; d < 16; ++d) a += a_lds[ss][d] * wav[d];
            acca[ss] = a;
        }
        // scatter: o -> (head8, k/q, c)
        const int h8 = o >> 7;
        const int rem = o & 127;
        const int isq = rem >> 6;
        const int c = rem & 63;
        float* dst = isq ? qbuf : kbuf;
        #pragma unroll
        for (int ss = 0; ss < 16; ++ss) {
            const size_t s = s0 + ss;
            dst[(s * NHEADS + h8) * HC + c]        = accn[ss];
            dst[(s * NHEADS + 8 + h8) * HC + c]    = accp[ss];
            dst[(s * NHEADS + 16 + h8) * HC + c]   = acca[ss];
        }
    }
}

// ---------------- K2: val GEMM ----------------
// grid 256: sb = bid&127 (16 s-rows), oh = bid>>7 (3072 of 6144 outputs)
__global__ __launch_bounds__(256) void val_kernel(
    const float* __restrict__ nodes, const float* __restrict__ Wv,
    const float* __restrict__ bv, float* __restrict__ vbuf)
{
    __shared__ float n_lds[16][256];
    const int tid = threadIdx.x;
    const int sb = blockIdx.x & 127;
    const int oh = blockIdx.x >> 7;
    const int s0 = sb * 16;

    #pragma unroll
    for (int p = 0; p < 4; ++p) {
        int u = tid * 4 + p;
        int r = u >> 6, c4 = u & 63;
        float4 v = *(const float4*)(nodes + (size_t)(s0 + r) * ND + c4 * 4);
        *(float4*)(&n_lds[r][c4 * 4]) = v;
    }
    __syncthreads();

    for (int rr = 0; rr < 12; ++rr) {
        const int o = oh * 3072 + rr * 256 + tid;  // 0..6143
        float acc[16];
        const float b = bv[o];
        #pragma unroll
        for (int ss = 0; ss < 16; ++ss) acc[ss] = b;
        const float4* wrow = (const float4*)(Wv + (size_t)o * ND);
        for (int d4 = 0; d4 < 64; ++d4) {
            float4 w = wrow[d4];
            #pragma unroll
            for (int ss = 0; ss < 16; ++ss) {
                const float* n = &n_lds[ss][d4 * 4];
                acc[ss] += n[0] * w.x + n[1] * w.y + n[2] * w.z + n[3] * w.w;
            }
        }
        #pragma unroll
        for (int ss = 0; ss < 16; ++ss)
            vbuf[(size_t)(s0 + ss) * VROW + o] = acc[ss];
    }
}

// ---------------- K3: flash attention (fp32) ----------------
// grid 768 = 32 i-tiles x 24 heads. block 256 thr.
// roles: QK: (ilq = tid>>2 in [0,64), jg = tid&3); PV: (ilg = tid>>4 in [0,16), dg = tid&15)
__global__ __launch_bounds__(256, 2) void attn_kernel(
    const float* __restrict__ kbuf, const float* __restrict__ qbuf,
    const float* __restrict__ vbuf, float* __restrict__ out)
{
    __shared__ float k_lds[64][68];
    __shared__ float q_lds[32][68];
    __shared__ float v_lds[32][260];
    __shared__ float att_lds[64][33];
    __shared__ float m_sm[64], l_sm[64], sc_sm[64];
    __shared__ float red_mx[64][4], red_sm[64][4];

    const int tid = threadIdx.x;
    const int bid = blockIdx.x;
    const int wg = (bid & 7) * 96 + (bid >> 3);  // XCD-chunked swizzle, 768%8==0 bijective
    const int it = wg & 31;
    const int h = wg >> 5;
    const int i0 = it * 64;

    #pragma unroll
    for (int p = 0; p < 4; ++p) {
        int u = tid * 4 + p;          // 0..1023 (64 rows x 16 f4)
        int r = u >> 4, c4 = u & 15;
        float4 v = *(const float4*)(kbuf + ((size_t)(i0 + r) * NHEADS + h) * HC + c4 * 4);
        *(float4*)(&k_lds[r][c4 * 4]) = v;
    }
    if (tid < 64) { m_sm[tid] = -1e30f; l_sm[tid] = 0.f; }
    __syncthreads();

    const int ilq = tid >> 2, jg = tid & 3;
    const int ilg = tid >> 4, dg = tid & 15;

    float4 kreg[16];
    #pragma unroll
    for (int c4 = 0; c4 < 16; ++c4) kreg[c4] = *(const float4*)(&k_lds[ilq][c4 * 4]);

    float4 acc[4][4];
    #pragma unroll
    for (int r = 0; r < 4; ++r)
        #pragma unroll
        for (int d = 0; d < 4; ++d) acc[r][d] = make_float4(0.f, 0.f, 0.f, 0.f);

    for (int jt = 0; jt < 64; ++jt) {
        const int j0 = jt * 32;
        __syncthreads();  // prior PV readers done before restage
        {   // stage q: 32x64 = 512 f4, 2 consecutive per thread
            int u = tid * 2;
            int r = u >> 4, c4 = u & 15;
            const float4* src = (const float4*)(qbuf + ((size_t)(j0 + r) * NHEADS + h) * HC);
            float4 a = src[c4], b = src[c4 + 1];
            float4* dst = (float4*)(&q_lds[r][0]);
            dst[c4] = a; dst[c4 + 1] = b;
        }
        #pragma unroll
        for (int p = 0; p < 8; ++p) {  // stage v: 32x256 = 2048 f4
            int u = tid * 8 + p;
            int r = u >> 6, c4 = u & 63;
            float4 v = *(const float4*)(vbuf + (size_t)(j0 + r) * VROW + h * ND + c4 * 4);
            *(float4*)(&v_lds[r][c4 * 4]) = v;
        }
        __syncthreads();

        // QK^T: 8 j's per thread
        float lg[8];
        #pragma unroll
        for (int jj = 0; jj < 8; ++jj) {
            const int j = jj * 4 + jg;
            const float4* qr = (const float4*)(&q_lds[j][0]);
            float sx = 0.f, sy = 0.f, sz = 0.f, sw = 0.f;
            #pragma unroll
            for (int c4 = 0; c4 < 16; ++c4) {
                float4 qq = qr[c4];
                sx += kreg[c4].x * qq.x;
                sy += kreg[c4].y * qq.y;
                sz += kreg[c4].z * qq.z;
                sw += kreg[c4].w * qq.w;
            }
            lg[jj] = (sx + sy) + (sz + sw);
        }
        float tm = lg[0];
        #pragma unroll
        for (int jj = 1; jj < 8; ++jj) tm = fmaxf(tm, lg[jj]);
        red_mx[ilq][jg] = tm;
        __syncthreads();
        const float m_old = m_sm[ilq];
        const float Mt = fmaxf(fmaxf(red_mx[ilq][0], red_mx[ilq][1]),
                               fmaxf(red_mx[ilq][2], red_mx[ilq][3]));
        const float m_new = fmaxf(m_old, Mt);
        float ps = 0.f;
        #pragma unroll
        for (int jj = 0; jj < 8; ++jj) {
            float p = __expf(lg[jj] - m_new);
            att_lds[ilq][jj * 4 + jg] = p;
            ps += p;
        }
        red_sm[ilq][jg] = ps;
        __syncthreads();
        if (jg == 0) {
            float sc = __expf(m_old - m_new);
            l_sm[ilq] = l_sm[ilq] * sc +
                (red_sm[ilq][0] + red_sm[ilq][1] + red_sm[ilq][2] + red_sm[ilq][3]);
            m_sm[ilq] = m_new;
            sc_sm[ilq] = sc;
        }
        __syncthreads();

        // PV: rescale + accumulate
        float scr[4];
        #pragma unroll
        for (int r = 0; r < 4; ++r) scr[r] = sc_sm[ilg * 4 + r];
        #pragma unroll
        for (int r = 0; r < 4; ++r) {
            #pragma unroll
            for (int d = 0; d < 4; ++d) {
                acc[r][d].x *= scr[r]; acc[r][d].y *= scr[r];
                acc[r][d].z *= scr[r]; acc[r][d].w *= scr[r];
            }
        }
        for (int j = 0; j < 32; ++j) {
            const float a0 = att_lds[ilg * 4 + 0][j];
            const float a1 = att_lds[ilg * 4 + 1][j];
            const float a2 = att_lds[ilg * 4 + 2][j];
            const float a3 = att_lds[ilg * 4 + 3][j];
            const float* vr = &v_lds[j][0];
            #pragma unroll
            for (int d = 0; d < 4; ++d) {
                float4 vv = *(const float4*)(vr + d * 64 + dg * 4);
                acc[0][d].x += a0 * vv.x; acc[0][d].y += a0 * vv.y; acc[0][d].z += a0 * vv.z; acc[0][d].w += a0 * vv.w;
                acc[1][d].x += a1 * vv.x; acc[1][d].y += a1 * vv.y; acc[1][d].z += a1 * vv.z; acc[1][d].w += a1 * vv.w;
                acc[2][d].x += a2 * vv.x; acc[2][d].y += a2 * vv.y; acc[2][d].z += a2 * vv.z; acc[2][d].w += a2 * vv.w;
                acc[3][d].x += a3 * vv.x; acc[3][d].y += a3 * vv.y; acc[3][d].z += a3 * vv.z; acc[3][d].w += a3 * vv.w;
            }
        }
    }

    // epilogue: normalize by l, sum over heads via atomics
    #pragma unroll
    for (int r = 0; r < 4; ++r) {
        const int row = i0 + ilg * 4 + r;
        const float inv = 1.f / l_sm[ilg * 4 + r];
        #pragma unroll
        for (int d = 0; d < 4; ++d) {
            float* op = out + (size_t)row * ND + d * 64 + dg * 4;
            atomicAdd(op + 0, acc[r][d].x * inv);
            atomicAdd(op + 1, acc[r][d].y * inv);
            atomicAdd(op + 2, acc[r][d].z * inv);
            atomicAdd(op + 3, acc[r][d].w * inv);
        }
    }
}

extern "C" void kernel_launch(void* const* d_in, const int* in_sizes, int n_in,
                              void* d_out, int out_size, void* d_ws, size_t ws_size,
                              hipStream_t stream) {
    const float* nodes = (const float*)d_in[0];
    const float* pos   = (const float*)d_in[1];
    const float* aux   = (const float*)d_in[2];
    const float* Wn    = (const float*)d_in[3];
    const float* bn    = (const float*)d_in[4];
    const float* Wp    = (const float*)d_in[5];
    const float* bp    = (const float*)d_in[6];
    const float* Wa    = (const float*)d_in[7];
    const float* Wv    = (const float*)d_in[8];
    const float* bv    = (const float*)d_in[9];
    float* out = (float*)d_out;

    const size_t KQ_ELEMS = (size_t)SLEN * NHEADS * HC;   // 3,145,728
    const size_t V_ELEMS  = (size_t)SLEN * NHEADS * ND;   // 12,582,912
    const size_t need = (2 * KQ_ELEMS + V_ELEMS) * sizeof(float);  // ~75.5 MB

    // zero output (head-sum accumulates via atomics)
    zero_out_kernel<<<512, 256, 0, stream>>>((float4*)out);

    if (ws_size < need) return;  // fail loudly (zeros) rather than corrupt

    float* kbuf = (float*)d_ws;
    float* qbuf = kbuf + KQ_ELEMS;
    float* vbuf = qbuf + KQ_ELEMS;

    kq_kernel<<<256, 256, 0, stream>>>(nodes, pos, aux, Wn, bn, Wp, bp, Wa, kbuf, qbuf);
    val_kernel<<<256, 256, 0, stream>>>(nodes, Wv, bv, vbuf);
    attn_kernel<<<768, 256, 0, stream>>>(kbuf, qbuf, vbuf, out);
}

// Round 2
// 622.435 us; speedup vs baseline: 2.5952x; 2.5952x over previous
//
#include <hip/hip_runtime.h>
#include <math.h>

#define SLEN 2048
#define ND 256
#define NH 24
#define HC 64
#define TWO_PI 6.283185307179586f

typedef __attribute__((ext_vector_type(8))) short short8;
typedef __attribute__((ext_vector_type(16))) float f32x16;

// XOR-swizzle for 128B-row LDS tiles: byte ^= ((row&7)<<4)
#define SWZ(b) ((b) ^ (((b) >> 3) & 0x70))

static __device__ __forceinline__ unsigned short f2bf(float f) {
    union { float f; unsigned int u; } v; v.f = f;
    unsigned int u = v.u;
    return (unsigned short)((u + 0x7FFFu + ((u >> 16) & 1u)) >> 16);
}
static __device__ __forceinline__ unsigned int pack2(float a, float b) {
    return (unsigned int)f2bf(a) | ((unsigned int)f2bf(b) << 16);
}

// ---------------- zero partial ----------------
__global__ __launch_bounds__(256) void zero_partial_kernel(float4* __restrict__ p) {
    p[(size_t)blockIdx.x * 256 + threadIdx.x] = make_float4(0.f, 0.f, 0.f, 0.f);
}

// ---------------- K1: k/q projections (fp32, unchanged) ----------------
__global__ __launch_bounds__(256) void kq_kernel(
    const float* __restrict__ nodes, const float* __restrict__ pos,
    const float* __restrict__ aux,
    const float* __restrict__ Wn, const float* __restrict__ bn,
    const float* __restrict__ Wp, const float* __restrict__ bp,
    const float* __restrict__ Wa,
    float* __restrict__ kbuf, float* __restrict__ qbuf)
{
    __shared__ float n_lds[16][256];
    __shared__ float pf_lds[16][6];
    __shared__ float a_lds[16][16];
    const int tid = threadIdx.x;
    const int sb = blockIdx.x & 127;
    const int oh = blockIdx.x >> 7;
    const int s0 = sb * 16;

    #pragma unroll
    for (int p = 0; p < 4; ++p) {
        int u = tid * 4 + p;
        int r = u >> 6, c4 = u & 63;
        float4 v = *(const float4*)(nodes + (size_t)(s0 + r) * ND + c4 * 4);
        *(float4*)(&n_lds[r][c4 * 4]) = v;
    }
    if (tid < 48) {
        int r = tid / 3, c = tid % 3;
        float pv = pos[(s0 + r) * 3 + c] * TWO_PI;
        pf_lds[r][c] = cosf(pv);
        pf_lds[r][c + 3] = sinf(pv);
    }
    if (tid < 256) {
        int r = tid >> 4, c = tid & 15;
        a_lds[r][c] = aux[(s0 + r) * 16 + c];
    }
    __syncthreads();

    for (int rr = 0; rr < 2; ++rr) {
        const int o = oh * 512 + rr * 256 + tid;
        float accn[16];
        const float bnv = bn[o];
        #pragma unroll
        for (int ss = 0; ss < 16; ++ss) accn[ss] = bnv;
        const float4* wrow = (const float4*)(Wn + (size_t)o * ND);
        for (int d4 = 0; d4 < 64; ++d4) {
            float4 w = wrow[d4];
            #pragma unroll
            for (int ss = 0; ss < 16; ++ss) {
                const float* n = &n_lds[ss][d4 * 4];
                accn[ss] += n[0] * w.x + n[1] * w.y + n[2] * w.z + n[3] * w.w;
            }
        }
        float accp[16];
        const float bpv = bp[o];
        float wpv[6];
        #pragma unroll
        for (int d = 0; d < 6; ++d) wpv[d] = Wp[(size_t)o * 6 + d];
        #pragma unroll
        for (int ss = 0; ss < 16; ++ss) {
            float a = bpv;
            #pragma unroll
            for (int d = 0; d < 6; ++d) a += pf_lds[ss][d] * wpv[d];
            accp[ss] = a;
        }
        float acca[16];
        float wav[16];
        #pragma unroll
        for (int d = 0; d < 16; ++d) wav[d] = Wa[(size_t)o * 16 + d];
        #pragma unroll
        for (int ss = 0; ss < 16; ++ss) {
            float a = 0.f;
            #pragma unroll
            for (int d = 0; d < 16; ++d) a += a_lds[ss][d] * wav[d];
            acca[ss] = a;
        }
        const int h8 = o >> 7;
        const int rem = o & 127;
        const int isq = rem >> 6;
        const int c = rem & 63;
        float* dst = isq ? qbuf : kbuf;
        #pragma unroll
        for (int ss = 0; ss < 16; ++ss) {
            const size_t s = s0 + ss;
            dst[(s * NH + h8) * HC + c]      = accn[ss];
            dst[(s * NH + 8 + h8) * HC + c]  = accp[ss];
            dst[(s * NH + 16 + h8) * HC + c] = acca[ss];
        }
    }
}

// ---------------- K2: val GEMM, output transposed bf16 vt[24][256][2048] ----------------
__global__ __launch_bounds__(256) void val_kernel(
    const float* __restrict__ nodes, const float* __restrict__ Wv,
    const float* __restrict__ bv, unsigned short* __restrict__ vt)
{
    __shared__ float n_lds[16][256];
    const int tid = threadIdx.x;
    const int sb = blockIdx.x & 127;
    const int oh = blockIdx.x >> 7;
    const int s0 = sb * 16;

    #pragma unroll
    for (int p = 0; p < 4; ++p) {
        int u = tid * 4 + p;
        int r = u >> 6, c4 = u & 63;
        float4 v = *(const float4*)(nodes + (size_t)(s0 + r) * ND + c4 * 4);
        *(float4*)(&n_lds[r][c4 * 4]) = v;
    }
    __syncthreads();

    for (int rr = 0; rr < 12; ++rr) {
        const int o = oh * 3072 + rr * 256 + tid;  // 0..6143 = hh*256 + d
        float acc[16];
        const float b = bv[o];
        #pragma unroll
        for (int ss = 0; ss < 16; ++ss) acc[ss] = b;
        const float4* wrow = (const float4*)(Wv + (size_t)o * ND);
        for (int d4 = 0; d4 < 64; ++d4) {
            float4 w = wrow[d4];
            #pragma unroll
            for (int ss = 0; ss < 16; ++ss) {
                const float* n = &n_lds[ss][d4 * 4];
                acc[ss] += n[0] * w.x + n[1] * w.y + n[2] * w.z + n[3] * w.w;
            }
        }
        uint4 lo, hi;
        lo.x = pack2(acc[0], acc[1]);  lo.y = pack2(acc[2], acc[3]);
        lo.z = pack2(acc[4], acc[5]);  lo.w = pack2(acc[6], acc[7]);
        hi.x = pack2(acc[8], acc[9]);  hi.y = pack2(acc[10], acc[11]);
        hi.z = pack2(acc[12], acc[13]); hi.w = pack2(acc[14], acc[15]);
        const size_t base = (size_t)o * SLEN + s0;   // o = hh*256+d -> [hh][d][s]
        *(uint4*)(&vt[base]) = lo;
        *(uint4*)(&vt[base + 8]) = hi;
    }
}

// ---------------- K3: flash attention, bf16 MFMA 32x32x16 ----------------
// grid 384 = 24 heads x 16 i-tiles of 128 rows; 4 waves x 32 rows each.
// Swapped QK^T (S^T = q @ k^T): softmax axis j is lane-local (i = lane&31).
__global__ __launch_bounds__(256, 2) void attn_kernel(
    const float* __restrict__ kbuf, const float* __restrict__ qbuf,
    const unsigned short* __restrict__ vt, float* __restrict__ partial)
{
    __shared__ __align__(16) char q_raw[64 * 128];       // [j][c] bf16, swizzled
    __shared__ __align__(16) char vt_raw[256 * 128];     // [d][j] bf16, swizzled
    __shared__ __align__(16) char p_raw[4][32 * 128];    // per-wave [i][j] bf16, swizzled
    __shared__ float sc_sm[4][32];

    const int tid = threadIdx.x;
    const int w = tid >> 6, lane = tid & 63;
    const int l31 = lane & 31, lh = lane >> 5;
    const int wg = (blockIdx.x & 7) * 48 + (blockIdx.x >> 3);  // XCD-chunked, bijective
    const int h = wg >> 4, it = wg & 15;
    const int i0 = it * 128;

    // persistent k fragments: this wave's 32 rows, K=c in 4 steps of 16
    short8 kf[4];
    {
        const float* kp = kbuf + ((size_t)(i0 + w * 32 + l31) * NH + h) * HC + lh * 8;
        #pragma unroll
        for (int ks = 0; ks < 4; ++ks) {
            float4 x = *(const float4*)(kp + ks * 16);
            float4 y = *(const float4*)(kp + ks * 16 + 4);
            short8 f;
            f[0] = (short)f2bf(x.x); f[1] = (short)f2bf(x.y);
            f[2] = (short)f2bf(x.z); f[3] = (short)f2bf(x.w);
            f[4] = (short)f2bf(y.x); f[5] = (short)f2bf(y.y);
            f[6] = (short)f2bf(y.z); f[7] = (short)f2bf(y.w);
            kf[ks] = f;
        }
    }

    f32x16 acc[8];
    #pragma unroll
    for (int nf = 0; nf < 8; ++nf)
        #pragma unroll
        for (int r = 0; r < 16; ++r) acc[nf][r] = 0.f;
    float m_run = -1e30f, l_run = 0.f;

    for (int jt = 0; jt < SLEN / 64; ++jt) {
        const int j0 = jt * 64;
        __syncthreads();
        {   // stage q tile [64][64] fp32 -> bf16 swizzled
            const int j = tid >> 2, cq = (tid & 3) * 16;
            const float* src = qbuf + ((size_t)(j0 + j) * NH + h) * HC + cq;
            float4 a = ((const float4*)src)[0], b = ((const float4*)src)[1],
                   c = ((const float4*)src)[2], d = ((const float4*)src)[3];
            uint4 u0, u1;
            u0.x = pack2(a.x, a.y); u0.y = pack2(a.z, a.w);
            u0.z = pack2(b.x, b.y); u0.w = pack2(b.z, b.w);
            u1.x = pack2(c.x, c.y); u1.y = pack2(c.z, c.w);
            u1.z = pack2(d.x, d.y); u1.w = pack2(d.z, d.w);
            const int byte = j * 128 + cq * 2;
            *(uint4*)(q_raw + SWZ(byte)) = u0;
            *(uint4*)(q_raw + SWZ(byte + 16)) = u1;
        }
        {   // stage v^T tile [256][64] bf16 swizzled
            const int dr = tid >> 3, j8 = (tid & 7) * 8;
            #pragma unroll
            for (int p = 0; p < 8; ++p) {
                const int d = p * 32 + dr;
                uint4 v = *(const uint4*)(vt + ((size_t)h * 256 + d) * SLEN + j0 + j8);
                *(uint4*)(vt_raw + SWZ(d * 128 + j8 * 2)) = v;
            }
        }
        __syncthreads();

        // QK^T: S^T[j, i], j in two 32-blocks
        f32x16 s0, s1;
        #pragma unroll
        for (int r = 0; r < 16; ++r) { s0[r] = 0.f; s1[r] = 0.f; }
        #pragma unroll
        for (int ks = 0; ks < 4; ++ks) {
            short8 a0 = *(const short8*)(q_raw + SWZ(l31 * 128 + ks * 32 + lh * 16));
            short8 a1 = *(const short8*)(q_raw + SWZ((32 + l31) * 128 + ks * 32 + lh * 16));
            s0 = __builtin_amdgcn_mfma_f32_32x32x16_bf16(a0, kf[ks], s0, 0, 0, 0);
            s1 = __builtin_amdgcn_mfma_f32_32x32x16_bf16(a1, kf[ks], s1, 0, 0, 0);
        }

        // online softmax (i = lane&31 fixed per lane; 32 j-values per lane)
        float tmax = s0[0];
        #pragma unroll
        for (int r = 1; r < 16; ++r) tmax = fmaxf(tmax, s0[r]);
        #pragma unroll
        for (int r = 0; r < 16; ++r) tmax = fmaxf(tmax, s1[r]);
        tmax = fmaxf(tmax, __shfl_xor(tmax, 32));

        if (!__all(tmax - m_run <= 8.0f)) {   // defer-max (T13)
            const float mnew = fmaxf(m_run, tmax);
            const float sc = __expf(m_run - mnew);
            l_run *= sc; m_run = mnew;
            if (lane < 32) sc_sm[w][l31] = sc;
            asm volatile("s_waitcnt lgkmcnt(0)" ::: "memory");
            float scv[16];
            #pragma unroll
            for (int r = 0; r < 16; ++r)
                scv[r] = sc_sm[w][(r & 3) + 8 * (r >> 2) + 4 * lh];
            #pragma unroll
            for (int nf = 0; nf < 8; ++nf)
                #pragma unroll
                for (int r = 0; r < 16; ++r) acc[nf][r] *= scv[r];
        }

        // P = exp(S - m), store bf16 to per-wave p tile, accumulate row-sum
        float psum = 0.f;
        #pragma unroll
        for (int mf = 0; mf < 2; ++mf) {
            #pragma unroll
            for (int qg = 0; qg < 4; ++qg) {
                float e0, e1, e2, e3;
                if (mf == 0) {
                    e0 = __expf(s0[qg * 4 + 0] - m_run); e1 = __expf(s0[qg * 4 + 1] - m_run);
                    e2 = __expf(s0[qg * 4 + 2] - m_run); e3 = __expf(s0[qg * 4 + 3] - m_run);
                } else {
                    e0 = __expf(s1[qg * 4 + 0] - m_run); e1 = __expf(s1[qg * 4 + 1] - m_run);
                    e2 = __expf(s1[qg * 4 + 2] - m_run); e3 = __expf(s1[qg * 4 + 3] - m_run);
                }
                psum += (e0 + e1) + (e2 + e3);
                uint2 u; u.x = pack2(e0, e1); u.y = pack2(e2, e3);
                const int jb = mf * 32 + qg * 8 + lh * 4;
                *(uint2*)(p_raw[w] + SWZ(l31 * 128 + jb * 2)) = u;
            }
        }
        psum += __shfl_xor(psum, 32);
        l_run += psum;

        // PV: out[i, d] += P[i, j] * v[j, d]
        #pragma unroll
        for (int ks = 0; ks < 4; ++ks) {
            short8 pa = *(const short8*)(p_raw[w] + SWZ(l31 * 128 + (ks * 16 + lh * 8) * 2));
            #pragma unroll
            for (int nf = 0; nf < 8; ++nf) {
                short8 vb = *(const short8*)(vt_raw + SWZ((nf * 32 + l31) * 128 + (ks * 16 + lh * 8) * 2));
                acc[nf] = __builtin_amdgcn_mfma_f32_32x32x16_bf16(pa, vb, acc[nf], 0, 0, 0);
            }
        }
    }

    // epilogue: divide by l, add into per-head-group partial
    if (lane < 32) sc_sm[w][l31] = 1.0f / l_run;
    asm volatile("s_waitcnt lgkmcnt(0)" ::: "memory");
    float lv[16];
    #pragma unroll
    for (int r = 0; r < 16; ++r)
        lv[r] = sc_sm[w][(r & 3) + 8 * (r >> 2) + 4 * lh];
    float* pb = partial + (size_t)(h / 3) * (SLEN * ND);
    #pragma unroll
    for (int nf = 0; nf < 8; ++nf) {
        const int d = nf * 32 + l31;
        #pragma unroll
        for (int r = 0; r < 16; ++r) {
            const int i = i0 + w * 32 + (r & 3) + 8 * (r >> 2) + 4 * lh;
            atomicAdd(pb + (size_t)i * ND + d, acc[nf][r] * lv[r]);
        }
    }
}

// ---------------- K4: reduce 8 partials -> out ----------------
__global__ __launch_bounds__(256) void reduce_kernel(
    const float4* __restrict__ partial, float4* __restrict__ out)
{
    const size_t id = (size_t)blockIdx.x * 256 + threadIdx.x;  // 131072 float4s
    float4 s = make_float4(0.f, 0.f, 0.f, 0.f);
    #pragma unroll
    for (int g = 0; g < 8; ++g) {
        float4 v = partial[g * (SLEN * ND / 4) + id];
        s.x += v.x; s.y += v.y; s.z += v.z; s.w += v.w;
    }
    out[id] = s;
}

extern "C" void kernel_launch(void* const* d_in, const int* in_sizes, int n_in,
                              void* d_out, int out_size, void* d_ws, size_t ws_size,
                              hipStream_t stream) {
    const float* nodes = (const float*)d_in[0];
    const float* pos   = (const float*)d_in[1];
    const float* aux   = (const float*)d_in[2];
    const float* Wn    = (const float*)d_in[3];
    const float* bn    = (const float*)d_in[4];
    const float* Wp    = (const float*)d_in[5];
    const float* bp    = (const float*)d_in[6];
    const float* Wa    = (const float*)d_in[7];
    const float* Wv    = (const float*)d_in[8];
    const float* bv    = (const float*)d_in[9];
    float* out = (float*)d_out;

    const size_t KQ = (size_t)SLEN * NH * HC;          // 3,145,728 floats each
    const size_t VT = (size_t)NH * ND * SLEN;          // 12,582,912 bf16
    const size_t PART = (size_t)8 * SLEN * ND;         // 4,194,304 floats
    const size_t need = 2 * KQ * 4 + VT * 2 + PART * 4;  // ~67 MB

    if (ws_size < need) return;

    float* kbuf = (float*)d_ws;
    float* qbuf = kbuf + KQ;
    unsigned short* vt = (unsigned short*)(qbuf + KQ);
    float* partial = (float*)(vt + VT);

    zero_partial_kernel<<<PART / 1024, 256, 0, stream>>>((float4*)partial);
    kq_kernel<<<256, 256, 0, stream>>>(nodes, pos, aux, Wn, bn, Wp, bp, Wa, kbuf, qbuf);
    val_kernel<<<256, 256, 0, stream>>>(nodes, Wv, bv, vt);
    attn_kernel<<<384, 256, 0, stream>>>(kbuf, qbuf, vt, partial);
    reduce_kernel<<<512, 256, 0, stream>>>((const float4*)partial, (float4*)out);
}

// Round 3
// 288.610 us; speedup vs baseline: 5.5969x; 2.1567x over previous
//
#include <hip/hip_runtime.h>
#include <math.h>

#define SLEN 2048
#define ND 256
#define NH 24
#define HC 64
#define TWO_PI 6.283185307179586f

typedef __attribute__((ext_vector_type(8))) short short8;
typedef __attribute__((ext_vector_type(16))) float f32x16;

// XOR-swizzle for 128B-row LDS tiles: byte ^= ((row&7)<<4)
#define SWZ(b) ((b) ^ (((b) >> 3) & 0x70))

static __device__ __forceinline__ unsigned short f2bf(float f) {
    union { float f; unsigned int u; } v; v.f = f;
    unsigned int u = v.u;
    return (unsigned short)((u + 0x7FFFu + ((u >> 16) & 1u)) >> 16);
}
static __device__ __forceinline__ unsigned int pack2(float a, float b) {
    return (unsigned int)f2bf(a) | ((unsigned int)f2bf(b) << 16);
}
static __device__ __forceinline__ void gload_lds16(const void* g, void* l) {
    __builtin_amdgcn_global_load_lds(
        (const __attribute__((address_space(1))) void*)(g),
        (__attribute__((address_space(3))) void*)(l), 16, 0, 0);
}

// ---------------- zero partial ----------------
__global__ __launch_bounds__(256) void zero_partial_kernel(float4* __restrict__ p) {
    p[(size_t)blockIdx.x * 256 + threadIdx.x] = make_float4(0.f, 0.f, 0.f, 0.f);
}

// ---------------- fp32 -> bf16 convert ----------------
__global__ __launch_bounds__(256) void f32_to_bf16_kernel(
    const float4* __restrict__ in, uint2* __restrict__ out) {
    const size_t id = (size_t)blockIdx.x * 256 + threadIdx.x;
    float4 v = in[id];
    uint2 u; u.x = pack2(v.x, v.y); u.y = pack2(v.z, v.w);
    out[id] = u;
}

// ---------------- K1: k/q projections (fp32) ----------------
__global__ __launch_bounds__(256) void kq_kernel(
    const float* __restrict__ nodes, const float* __restrict__ pos,
    const float* __restrict__ aux,
    const float* __restrict__ Wn, const float* __restrict__ bn,
    const float* __restrict__ Wp, const float* __restrict__ bp,
    const float* __restrict__ Wa,
    float* __restrict__ kbuf, float* __restrict__ qbuf)
{
    __shared__ float n_lds[16][256];
    __shared__ float pf_lds[16][6];
    __shared__ float a_lds[16][16];
    const int tid = threadIdx.x;
    const int sb = blockIdx.x & 127;
    const int oh = blockIdx.x >> 7;
    const int s0 = sb * 16;

    #pragma unroll
    for (int p = 0; p < 4; ++p) {
        int u = tid * 4 + p;
        int r = u >> 6, c4 = u & 63;
        float4 v = *(const float4*)(nodes + (size_t)(s0 + r) * ND + c4 * 4);
        *(float4*)(&n_lds[r][c4 * 4]) = v;
    }
    if (tid < 48) {
        int r = tid / 3, c = tid % 3;
        float pv = pos[(s0 + r) * 3 + c] * TWO_PI;
        pf_lds[r][c] = cosf(pv);
        pf_lds[r][c + 3] = sinf(pv);
    }
    if (tid < 256) {
        int r = tid >> 4, c = tid & 15;
        a_lds[r][c] = aux[(s0 + r) * 16 + c];
    }
    __syncthreads();

    for (int rr = 0; rr < 2; ++rr) {
        const int o = oh * 512 + rr * 256 + tid;
        float accn[16];
        const float bnv = bn[o];
        #pragma unroll
        for (int ss = 0; ss < 16; ++ss) accn[ss] = bnv;
        const float4* wrow = (const float4*)(Wn + (size_t)o * ND);
        for (int d4 = 0; d4 < 64; ++d4) {
            float4 w = wrow[d4];
            #pragma unroll
            for (int ss = 0; ss < 16; ++ss) {
                const float* n = &n_lds[ss][d4 * 4];
                accn[ss] += n[0] * w.x + n[1] * w.y + n[2] * w.z + n[3] * w.w;
            }
        }
        float accp[16];
        const float bpv = bp[o];
        float wpv[6];
        #pragma unroll
        for (int d = 0; d < 6; ++d) wpv[d] = Wp[(size_t)o * 6 + d];
        #pragma unroll
        for (int ss = 0; ss < 16; ++ss) {
            float a = bpv;
            #pragma unroll
            for (int d = 0; d < 6; ++d) a += pf_lds[ss][d] * wpv[d];
            accp[ss] = a;
        }
        float acca[16];
        float wav[16];
        #pragma unroll
        for (int d = 0; d < 16; ++d) wav[d] = Wa[(size_t)o * 16 + d];
        #pragma unroll
        for (int ss = 0; ss < 16; ++ss) {
            float a = 0.f;
            #pragma unroll
            for (int d = 0; d < 16; ++d) a += a_lds[ss][d] * wav[d];
            acca[ss] = a;
        }
        const int h8 = o >> 7;
        const int rem = o & 127;
        const int isq = rem >> 6;
        const int c = rem & 63;
        float* dst = isq ? qbuf : kbuf;
        #pragma unroll
        for (int ss = 0; ss < 16; ++ss) {
            const size_t s = s0 + ss;
            dst[(s * NH + h8) * HC + c]      = accn[ss];
            dst[(s * NH + 8 + h8) * HC + c]  = accp[ss];
            dst[(s * NH + 16 + h8) * HC + c] = acca[ss];
        }
    }
}

// ---------------- K2: val GEMM via MFMA -> vt[6144][2048] bf16 ----------------
// C[o][s] = sum_k Wv[o][k] * nodes[s][k] + bv[o].
// Block tile 128(o) x 128(s), full K=256 in LDS (2 x 64KB, 5-bit XOR swizzle).
// 4 waves, each 64x64 via 2x2 of mfma_32x32x16_bf16.
__global__ __launch_bounds__(256) void val_mfma_kernel(
    const unsigned short* __restrict__ wv_bf, const unsigned short* __restrict__ nodes_bf,
    const float* __restrict__ bv, unsigned short* __restrict__ vt)
{
    __shared__ __align__(16) char lds[131072];  // A: [128 rows][512B], B at +65536
    const int tid = threadIdx.x;
    const int w = tid >> 6, lane = tid & 63;
    const int l31 = lane & 31, lh = lane >> 5;
    const int wg = ((blockIdx.x & 7) * 96) + (blockIdx.x >> 3);  // XCD chunk, bijective
    const int o0 = (wg >> 4) * 128;
    const int s0 = (wg & 15) * 128;

    // stage: wave w covers rows w*32..w*32+31 of each tile; 16 insts x 1KB (2 rows)
    {
        const int rbase = w * 32;
        const int roff = lane >> 5;            // row within inst
        const int slot = l31 * 16;             // swizzled byte-in-row
        #pragma unroll
        for (int i = 0; i < 16; ++i) {
            const int row = rbase + i * 2 + roff;
            const int colb = slot ^ ((row & 31) << 4);   // unswizzled byte
            gload_lds16(wv_bf + (((size_t)(o0 + row)) << 8) + (colb >> 1),
                        lds + (rbase + i * 2) * 512);
        }
        #pragma unroll
        for (int i = 0; i < 16; ++i) {
            const int row = rbase + i * 2 + roff;
            const int colb = slot ^ ((row & 31) << 4);
            gload_lds16(nodes_bf + (((size_t)(s0 + row)) << 8) + (colb >> 1),
                        lds + 65536 + (rbase + i * 2) * 512);
        }
    }
    __syncthreads();

    const int wm = w >> 1, wn = w & 1;
    f32x16 acc[2][2];
    #pragma unroll
    for (int mf = 0; mf < 2; ++mf)
        #pragma unroll
        for (int nf = 0; nf < 2; ++nf)
            #pragma unroll
            for (int r = 0; r < 16; ++r) acc[mf][nf][r] = 0.f;

    const char* Abase = lds;
    const char* Bbase = lds + 65536;
    #pragma unroll
    for (int kk = 0; kk < 16; ++kk) {
        short8 af[2], bq[2];
        #pragma unroll
        for (int mf = 0; mf < 2; ++mf) {
            const int row = wm * 64 + mf * 32 + l31;
            af[mf] = *(const short8*)(Abase + row * 512 +
                     ((kk * 32 + lh * 16) ^ ((row & 31) << 4)));
        }
        #pragma unroll
        for (int nf = 0; nf < 2; ++nf) {
            const int row = wn * 64 + nf * 32 + l31;
            bq[nf] = *(const short8*)(Bbase + row * 512 +
                     ((kk * 32 + lh * 16) ^ ((row & 31) << 4)));
        }
        #pragma unroll
        for (int mf = 0; mf < 2; ++mf)
            #pragma unroll
            for (int nf = 0; nf < 2; ++nf)
                acc[mf][nf] = __builtin_amdgcn_mfma_f32_32x32x16_bf16(
                    af[mf], bq[nf], acc[mf][nf], 0, 0, 0);
    }

    // store: C/D layout col=lane&31, row=(r&3)+8*(r>>2)+4*(lane>>5)
    #pragma unroll
    for (int mf = 0; mf < 2; ++mf) {
        #pragma unroll
        for (int r = 0; r < 16; ++r) {
            const int o = o0 + wm * 64 + mf * 32 + (r & 3) + 8 * (r >> 2) + 4 * lh;
            const float b = bv[o];
            #pragma unroll
            for (int nf = 0; nf < 2; ++nf) {
                const int s = s0 + wn * 64 + nf * 32 + l31;
                vt[(size_t)o * SLEN + s] = f2bf(acc[mf][nf][r] + b);
            }
        }
    }
}

// ---------------- K3: flash attention, bf16 MFMA 32x32x16 ----------------
// grid 384 = 24 heads x 16 i-tiles of 128 rows; 4 waves x 32 rows each.
// Swapped QK^T (S^T = q @ k^T): softmax axis j is lane-local (i = lane&31).
__global__ __launch_bounds__(256, 2) void attn_kernel(
    const float* __restrict__ kbuf, const float* __restrict__ qbuf,
    const unsigned short* __restrict__ vt, float* __restrict__ partial)
{
    __shared__ __align__(16) char q_raw[64 * 128];       // [j][c] bf16, swizzled
    __shared__ __align__(16) char vt_raw[256 * 128];     // [d][j] bf16, swizzled
    __shared__ __align__(16) char p_raw[4][32 * 128];    // per-wave [i][j] bf16, swizzled
    __shared__ float sc_sm[4][32];

    const int tid = threadIdx.x;
    const int w = tid >> 6, lane = tid & 63;
    const int l31 = lane & 31, lh = lane >> 5;
    const int wg = (blockIdx.x & 7) * 48 + (blockIdx.x >> 3);  // XCD-chunked, bijective
    const int h = wg >> 4, it = wg & 15;
    const int i0 = it * 128;

    // persistent k fragments: this wave's 32 rows, K=c in 4 steps of 16
    short8 kf[4];
    {
        const float* kp = kbuf + ((size_t)(i0 + w * 32 + l31) * NH + h) * HC + lh * 8;
        #pragma unroll
        for (int ks = 0; ks < 4; ++ks) {
            float4 x = *(const float4*)(kp + ks * 16);
            float4 y = *(const float4*)(kp + ks * 16 + 4);
            short8 f;
            f[0] = (short)f2bf(x.x); f[1] = (short)f2bf(x.y);
            f[2] = (short)f2bf(x.z); f[3] = (short)f2bf(x.w);
            f[4] = (short)f2bf(y.x); f[5] = (short)f2bf(y.y);
            f[6] = (short)f2bf(y.z); f[7] = (short)f2bf(y.w);
            kf[ks] = f;
        }
    }

    f32x16 acc[8];
    #pragma unroll
    for (int nf = 0; nf < 8; ++nf)
        #pragma unroll
        for (int r = 0; r < 16; ++r) acc[nf][r] = 0.f;
    float m_run = -1e30f, l_run = 0.f;

    for (int jt = 0; jt < SLEN / 64; ++jt) {
        const int j0 = jt * 64;
        __syncthreads();
        {   // stage q tile [64][64] fp32 -> bf16 swizzled
            const int j = tid >> 2, cq = (tid & 3) * 16;
            const float* src = qbuf + ((size_t)(j0 + j) * NH + h) * HC + cq;
            float4 a = ((const float4*)src)[0], b = ((const float4*)src)[1],
                   c = ((const float4*)src)[2], d = ((const float4*)src)[3];
            uint4 u0, u1;
            u0.x = pack2(a.x, a.y); u0.y = pack2(a.z, a.w);
            u0.z = pack2(b.x, b.y); u0.w = pack2(b.z, b.w);
            u1.x = pack2(c.x, c.y); u1.y = pack2(c.z, c.w);
            u1.z = pack2(d.x, d.y); u1.w = pack2(d.z, d.w);
            const int byte = j * 128 + cq * 2;
            *(uint4*)(q_raw + SWZ(byte)) = u0;
            *(uint4*)(q_raw + SWZ(byte + 16)) = u1;
        }
        {   // stage v^T tile [256][64] bf16 swizzled
            const int dr = tid >> 3, j8 = (tid & 7) * 8;
            #pragma unroll
            for (int p = 0; p < 8; ++p) {
                const int d = p * 32 + dr;
                uint4 v = *(const uint4*)(vt + ((size_t)h * 256 + d) * SLEN + j0 + j8);
                *(uint4*)(vt_raw + SWZ(d * 128 + j8 * 2)) = v;
            }
        }
        __syncthreads();

        // QK^T: S^T[j, i], j in two 32-blocks
        f32x16 s0, s1;
        #pragma unroll
        for (int r = 0; r < 16; ++r) { s0[r] = 0.f; s1[r] = 0.f; }
        #pragma unroll
        for (int ks = 0; ks < 4; ++ks) {
            short8 a0 = *(const short8*)(q_raw + SWZ(l31 * 128 + ks * 32 + lh * 16));
            short8 a1 = *(const short8*)(q_raw + SWZ((32 + l31) * 128 + ks * 32 + lh * 16));
            s0 = __builtin_amdgcn_mfma_f32_32x32x16_bf16(a0, kf[ks], s0, 0, 0, 0);
            s1 = __builtin_amdgcn_mfma_f32_32x32x16_bf16(a1, kf[ks], s1, 0, 0, 0);
        }

        // online softmax (i = lane&31 fixed per lane; 32 j-values per lane)
        float tmax = s0[0];
        #pragma unroll
        for (int r = 1; r < 16; ++r) tmax = fmaxf(tmax, s0[r]);
        #pragma unroll
        for (int r = 0; r < 16; ++r) tmax = fmaxf(tmax, s1[r]);
        tmax = fmaxf(tmax, __shfl_xor(tmax, 32));

        if (!__all(tmax - m_run <= 8.0f)) {   // defer-max (T13)
            const float mnew = fmaxf(m_run, tmax);
            const float sc = __expf(m_run - mnew);
            l_run *= sc; m_run = mnew;
            if (lane < 32) sc_sm[w][l31] = sc;
            asm volatile("s_waitcnt lgkmcnt(0)" ::: "memory");
            float scv[16];
            #pragma unroll
            for (int r = 0; r < 16; ++r)
                scv[r] = sc_sm[w][(r & 3) + 8 * (r >> 2) + 4 * lh];
            #pragma unroll
            for (int nf = 0; nf < 8; ++nf)
                #pragma unroll
                for (int r = 0; r < 16; ++r) acc[nf][r] *= scv[r];
        }

        // P = exp(S - m), store bf16 to per-wave p tile, accumulate row-sum
        float psum = 0.f;
        #pragma unroll
        for (int mf = 0; mf < 2; ++mf) {
            #pragma unroll
            for (int qg = 0; qg < 4; ++qg) {
                float e0, e1, e2, e3;
                if (mf == 0) {
                    e0 = __expf(s0[qg * 4 + 0] - m_run); e1 = __expf(s0[qg * 4 + 1] - m_run);
                    e2 = __expf(s0[qg * 4 + 2] - m_run); e3 = __expf(s0[qg * 4 + 3] - m_run);
                } else {
                    e0 = __expf(s1[qg * 4 + 0] - m_run); e1 = __expf(s1[qg * 4 + 1] - m_run);
                    e2 = __expf(s1[qg * 4 + 2] - m_run); e3 = __expf(s1[qg * 4 + 3] - m_run);
                }
                psum += (e0 + e1) + (e2 + e3);
                uint2 u; u.x = pack2(e0, e1); u.y = pack2(e2, e3);
                const int jb = mf * 32 + qg * 8 + lh * 4;
                *(uint2*)(p_raw[w] + SWZ(l31 * 128 + jb * 2)) = u;
            }
        }
        psum += __shfl_xor(psum, 32);
        l_run += psum;

        // PV: out[i, d] += P[i, j] * v[j, d]
        #pragma unroll
        for (int ks = 0; ks < 4; ++ks) {
            short8 pa = *(const short8*)(p_raw[w] + SWZ(l31 * 128 + (ks * 16 + lh * 8) * 2));
            #pragma unroll
            for (int nf = 0; nf < 8; ++nf) {
                short8 vb = *(const short8*)(vt_raw + SWZ((nf * 32 + l31) * 128 + (ks * 16 + lh * 8) * 2));
                acc[nf] = __builtin_amdgcn_mfma_f32_32x32x16_bf16(pa, vb, acc[nf], 0, 0, 0);
            }
        }
    }

    // epilogue: divide by l, add into per-head-group partial
    if (lane < 32) sc_sm[w][l31] = 1.0f / l_run;
    asm volatile("s_waitcnt lgkmcnt(0)" ::: "memory");
    float lv[16];
    #pragma unroll
    for (int r = 0; r < 16; ++r)
        lv[r] = sc_sm[w][(r & 3) + 8 * (r >> 2) + 4 * lh];
    float* pb = partial + (size_t)(h / 3) * (SLEN * ND);
    #pragma unroll
    for (int nf = 0; nf < 8; ++nf) {
        const int d = nf * 32 + l31;
        #pragma unroll
        for (int r = 0; r < 16; ++r) {
            const int i = i0 + w * 32 + (r & 3) + 8 * (r >> 2) + 4 * lh;
            atomicAdd(pb + (size_t)i * ND + d, acc[nf][r] * lv[r]);
        }
    }
}

// ---------------- K4: reduce 8 partials -> out ----------------
__global__ __launch_bounds__(256) void reduce_kernel(
    const float4* __restrict__ partial, float4* __restrict__ out)
{
    const size_t id = (size_t)blockIdx.x * 256 + threadIdx.x;  // 131072 float4s
    float4 s = make_float4(0.f, 0.f, 0.f, 0.f);
    #pragma unroll
    for (int g = 0; g < 8; ++g) {
        float4 v = partial[g * (SLEN * ND / 4) + id];
        s.x += v.x; s.y += v.y; s.z += v.z; s.w += v.w;
    }
    out[id] = s;
}

extern "C" void kernel_launch(void* const* d_in, const int* in_sizes, int n_in,
                              void* d_out, int out_size, void* d_ws, size_t ws_size,
                              hipStream_t stream) {
    const float* nodes = (const float*)d_in[0];
    const float* pos   = (const float*)d_in[1];
    const float* aux   = (const float*)d_in[2];
    const float* Wn    = (const float*)d_in[3];
    const float* bn    = (const float*)d_in[4];
    const float* Wp    = (const float*)d_in[5];
    const float* bp    = (const float*)d_in[6];
    const float* Wa    = (const float*)d_in[7];
    const float* Wv    = (const float*)d_in[8];
    const float* bv    = (const float*)d_in[9];
    float* out = (float*)d_out;

    const size_t KQ = (size_t)SLEN * NH * HC;          // 3,145,728 floats each
    const size_t VT = (size_t)NH * ND * SLEN;          // 12,582,912 bf16
    const size_t PART = (size_t)8 * SLEN * ND;         // 4,194,304 floats
    const size_t WVBF = (size_t)6144 * ND;             // 1,572,864 bf16
    const size_t NDBF = (size_t)SLEN * ND;             // 524,288 bf16
    const size_t need = 2 * KQ * 4 + VT * 2 + PART * 4 + (WVBF + NDBF) * 2;

    if (ws_size < need) return;

    float* kbuf = (float*)d_ws;
    float* qbuf = kbuf + KQ;
    unsigned short* vt = (unsigned short*)(qbuf + KQ);
    float* partial = (float*)(vt + VT);
    unsigned short* wv_bf = (unsigned short*)(partial + PART);
    unsigned short* nodes_bf = wv_bf + WVBF;

    zero_partial_kernel<<<PART / 1024, 256, 0, stream>>>((float4*)partial);
    f32_to_bf16_kernel<<<1536, 256, 0, stream>>>((const float4*)Wv, (uint2*)wv_bf);
    f32_to_bf16_kernel<<<512, 256, 0, stream>>>((const float4*)nodes, (uint2*)nodes_bf);
    kq_kernel<<<256, 256, 0, stream>>>(nodes, pos, aux, Wn, bn, Wp, bp, Wa, kbuf, qbuf);
    val_mfma_kernel<<<768, 256, 0, stream>>>(wv_bf, nodes_bf, bv, vt);
    attn_kernel<<<384, 256, 0, stream>>>(kbuf, qbuf, vt, partial);
    reduce_kernel<<<512, 256, 0, stream>>>((const float4*)partial, (float4*)out);
}